// Round 7
// baseline (110.212 us; speedup 1.0000x reference)
//
#include <hip/hip_runtime.h>

// AttentionalPoolingMechanism: fused single-pass attention pooling.
// A[64,512] f32, B[64,8192,256] f32, W[256,512] f32, b[256] f32 -> out[64,1,256] f32.
//
// AP = tanh(A@W^T + b); s_t = <AP_b, B[b,t,:]>; w_t = exp(-s_t)/sum; out = sum_t w_t B[b,t,:]
// No max-subtraction needed (reference does bare exp(-R); |s| <~ 40 fits f32).
//
// R7: revert SPLIT to 32 (R6 showed 1 resident generation loses the block
// backfill overlap; 2048 blocks / ~4 resident per CU = 2 generations is
// better). Single-variable A/B vs R5: drop the nontemporal flag on B loads
// (R4 bundled nt with the 8-row restructure; never isolated — nothing else
// needs L2, so caching B costs nothing, and nt may take a lower-efficiency
// TCC path).
// R2 lesson: no tight min-waves clamp ((256,4) capped VGPR=64 -> 484 MB spill).
// R4 lesson: clamped (non-peeled) prefetch re-read 64 MB from HBM.

#define BATCH 64
#define T_LEN 8192
#define FEAT 512
#define HID 256
#define SPLIT 32                       // blocks per batch in pool pass
#define ROWS_PER_BLOCK (T_LEN / SPLIT) // 256
#define ROWS_PER_WAVE (ROWS_PER_BLOCK / 4) // 64
#define ITERS (ROWS_PER_WAVE / 8)      // 8

typedef float f4 __attribute__((ext_vector_type(4)));

__device__ __forceinline__ float hsum(f4 v) { return (v.x + v.y) + (v.z + v.w); }

// DPP add: x + permuted(x). CTRL: 0xB1 quad_perm xor1, 0x4E quad_perm xor2,
// 0x128 row_ror:8, 0x124 row_ror:4 (row = 16 lanes).
template <int CTRL>
__device__ __forceinline__ float dpp_add(float x) {
    int y = __builtin_amdgcn_update_dpp(0, __float_as_int(x), CTRL, 0xF, 0xF, true);
    return x + __int_as_float(y);
}
__device__ __forceinline__ float row16_allreduce(float x) {
    x = dpp_add<0xB1>(x);
    x = dpp_add<0x4E>(x);
    x = dpp_add<0x128>(x);
    x = dpp_add<0x124>(x);
    return x;
}

// ---------------- Kernel 1: AP = tanh(A @ W^T + bias) ----------------
// grid (4, BATCH), 256 thr. Block (p,b) computes AP[b][p*64 .. p*64+63].
__global__ __launch_bounds__(256) void ap_kernel(const float* __restrict__ A,
                                                 const float* __restrict__ W,
                                                 const float* __restrict__ bias,
                                                 float* __restrict__ AP) {
    const int p = blockIdx.x;
    const int b = blockIdx.y;
    const int tid = threadIdx.x;
    const int pos = tid & 15;

    __shared__ float sA[FEAT];
    sA[tid] = A[b * FEAT + tid];
    sA[tid + 256] = A[b * FEAT + tid + 256];
    __syncthreads();

    const f4* sA4 = (const f4*)sA;
    f4 a0 = sA4[pos],      a1 = sA4[pos + 16], a2 = sA4[pos + 32], a3 = sA4[pos + 48];
    f4 a4 = sA4[pos + 64], a5 = sA4[pos + 80], a6 = sA4[pos + 96], a7 = sA4[pos + 112];

    #pragma unroll
    for (int pass = 0; pass < 4; ++pass) {
        const int h = p * 64 + pass * 16 + (tid >> 4);
        const f4* Wr = (const f4*)(W + (size_t)h * FEAT);
        f4 m = Wr[pos] * a0 + Wr[pos + 16] * a1 + Wr[pos + 32] * a2 + Wr[pos + 48] * a3
             + Wr[pos + 64] * a4 + Wr[pos + 80] * a5 + Wr[pos + 96] * a6 + Wr[pos + 112] * a7;
        float s = row16_allreduce(hsum(m));
        if (pos == 0) AP[b * HID + h] = tanhf(s + bias[h]);
    }
}

// ---------------- Kernel 2: fused score+exp+weighted-accumulate ----------------
// grid = (SPLIT, BATCH), 256 threads = 4 waves; wave owns 64 consecutive rows.
// Lane (sub = lane>>4, pos = lane&15): group-A row = base + sub, group-B row =
// base + 4 + sub. Per-instruction footprint: 4 rows x 256B contiguous segments.
__global__ __launch_bounds__(256) void pool_kernel(const float* __restrict__ B,
                                                   const float* __restrict__ AP,
                                                   float* __restrict__ numP,
                                                   float* __restrict__ denP) {
    const int split = blockIdx.x;
    const int b = blockIdx.y;
    const int tid = threadIdx.x;
    const int wv = tid >> 6;
    const int lane = tid & 63;
    const int sub = lane >> 4;
    const int pos = lane & 15;

    const f4* __restrict__ AP4 = (const f4*)(AP + b * HID);
    const f4 ap0 = AP4[pos];
    const f4 ap1 = AP4[pos + 16];
    const f4 ap2 = AP4[pos + 32];
    const f4 ap3 = AP4[pos + 48];

    const f4* __restrict__ B4 = (const f4*)(B) + (size_t)b * T_LEN * (HID / 4);
    const int row0 = split * ROWS_PER_BLOCK + wv * ROWS_PER_WAVE;

    f4 acc0 = {0.f,0.f,0.f,0.f}, acc1 = {0.f,0.f,0.f,0.f};
    f4 acc2 = {0.f,0.f,0.f,0.f}, acc3 = {0.f,0.f,0.f,0.f};
    float den = 0.0f;

    // prologue: load iteration 0 (rows base+sub and base+4+sub)
    const f4* pa = B4 + (size_t)(row0 + sub) * (HID / 4);
    const f4* pb = pa + 4 * (HID / 4);
    f4 vA0 = pa[pos], vA1 = pa[pos + 16], vA2 = pa[pos + 32], vA3 = pa[pos + 48];
    f4 vB0 = pb[pos], vB1 = pb[pos + 16], vB2 = pb[pos + 32], vB3 = pb[pos + 48];

    #pragma unroll
    for (int it = 0; it < ITERS; ++it) {
        // 1-iteration prefetch; PEELED on the last iteration (compile-time
        // under full unroll) — no redundant re-reads.
        f4 nA0, nA1, nA2, nA3, nB0, nB1, nB2, nB3;
        if (it + 1 < ITERS) {
            const f4* na = B4 + (size_t)(row0 + (it + 1) * 8 + sub) * (HID / 4);
            const f4* nb = na + 4 * (HID / 4);
            nA0 = na[pos]; nA1 = na[pos + 16]; nA2 = na[pos + 32]; nA3 = na[pos + 48];
            nB0 = nb[pos]; nB1 = nb[pos + 16]; nB2 = nb[pos + 32]; nB3 = nb[pos + 48];
        }

        f4 mA = vA0 * ap0 + vA1 * ap1 + vA2 * ap2 + vA3 * ap3;
        f4 mB = vB0 * ap0 + vB1 * ap1 + vB2 * ap2 + vB3 * ap3;
        float pAs = hsum(mA);
        float pBs = hsum(mB);

        // two independent 16-lane DPP allreduces — VALU-latency, interleaved
        pAs = dpp_add<0xB1>(pAs);  pBs = dpp_add<0xB1>(pBs);
        pAs = dpp_add<0x4E>(pAs);  pBs = dpp_add<0x4E>(pBs);
        pAs = dpp_add<0x128>(pAs); pBs = dpp_add<0x128>(pBs);
        pAs = dpp_add<0x124>(pAs); pBs = dpp_add<0x124>(pBs);

        const float wA = __expf(-pAs);
        const float wB = __expf(-pBs);
        acc0 += wA * vA0 + wB * vB0;
        acc1 += wA * vA1 + wB * vB1;
        acc2 += wA * vA2 + wB * vB2;
        acc3 += wA * vA3 + wB * vB3;
        den += wA + wB;

        if (it + 1 < ITERS) {
            vA0 = nA0; vA1 = nA1; vA2 = nA2; vA3 = nA3;
            vB0 = nB0; vB1 = nB1; vB2 = nB2; vB3 = nB3;
        }
    }

    // reduce accumulators across the 4 sub-groups (lane bits 4,5)
    #define XRED(x) x += __shfl_xor(x, 16, 64); x += __shfl_xor(x, 32, 64)
    XRED(acc0.x); XRED(acc0.y); XRED(acc0.z); XRED(acc0.w);
    XRED(acc1.x); XRED(acc1.y); XRED(acc1.z); XRED(acc1.w);
    XRED(acc2.x); XRED(acc2.y); XRED(acc2.z); XRED(acc2.w);
    XRED(acc3.x); XRED(acc3.y); XRED(acc3.z); XRED(acc3.w);
    XRED(den);
    #undef XRED

    // combine 4 waves via LDS, write per-block partials
    __shared__ float s_num[4][HID];
    __shared__ float s_den[4];
    if (sub == 0) {
        f4* dst = (f4*)s_num[wv];
        dst[pos]      = acc0;
        dst[pos + 16] = acc1;
        dst[pos + 32] = acc2;
        dst[pos + 48] = acc3;
    }
    if (lane == 0) s_den[wv] = den;
    __syncthreads();

    const int blk = b * SPLIT + split;
    float n = s_num[0][tid] + s_num[1][tid] + s_num[2][tid] + s_num[3][tid];
    numP[(size_t)blk * HID + tid] = n;
    if (tid == 0) denP[blk] = s_den[0] + s_den[1] + s_den[2] + s_den[3];
}

// ---------------- Kernel 3: reduce partials, normalize ----------------
__global__ __launch_bounds__(256) void reduce_kernel(const float* __restrict__ numP,
                                                     const float* __restrict__ denP,
                                                     float* __restrict__ out) {
    const int b = blockIdx.x;
    const int h = threadIdx.x;
    float num = 0.0f, den = 0.0f;
    #pragma unroll
    for (int s = 0; s < SPLIT; ++s) {
        num += numP[(size_t)(b * SPLIT + s) * HID + h];
        den += denP[b * SPLIT + s];
    }
    out[b * HID + h] = num / den;
}

extern "C" void kernel_launch(void* const* d_in, const int* in_sizes, int n_in,
                              void* d_out, int out_size, void* d_ws, size_t ws_size,
                              hipStream_t stream) {
    const float* A = (const float*)d_in[0];    // [64,512]
    const float* B = (const float*)d_in[1];    // [64,8192,256]
    const float* W = (const float*)d_in[2];    // [256,512]
    const float* bias = (const float*)d_in[3]; // [256]
    float* out = (float*)d_out;                // [64,1,256]

    float* AP = (float*)d_ws;
    float* numP = AP + BATCH * HID;
    float* denP = numP + BATCH * SPLIT * HID;

    ap_kernel<<<dim3(4, BATCH), 256, 0, stream>>>(A, W, bias, AP);
    pool_kernel<<<dim3(SPLIT, BATCH), 256, 0, stream>>>(B, AP, numP, denP);
    reduce_kernel<<<BATCH, 256, 0, stream>>>(numP, denP, out);
}

// Round 8
// 96.110 us; speedup vs baseline: 1.1467x; 1.1467x over previous
//
#include <hip/hip_runtime.h>

// AttentionalPoolingMechanism: fused single-pass attention pooling.
// A[64,512] f32, B[64,8192,256] f32, W[256,512] f32, b[256] f32 -> out[64,1,256] f32.
//
// AP = tanh(A@W^T + b); s_t = <AP_b, B[b,t,:]>; w_t = exp(-s_t)/sum; out = sum_t w_t B[b,t,:]
// No max-subtraction needed (reference does bare exp(-R); |s| <~ 40 fits f32).
//
// R8 = exact R5 (measured best, 96.85 µs). Config: SPLIT=32, nontemporal B
// loads, peeled last-iteration prefetch, 16-lane DPP allreduce, parallel ap.
// A/B evidence this is the practical optimum:
//   R6: SPLIT 16 (one resident generation) -> +1.3 µs (lost block backfill).
//   R7: cached (non-nt) B loads -> +13.4 µs (L2/L3 allocation overhead on a
//       pure 512 MB stream; nt bypass is a real win).
//   R2: tight launch_bounds clamp -> VGPR=64 spill, 484 MB scratch traffic.
//   R4: non-peeled prefetch + nt -> 64 MB redundant HBM re-reads.
// Pool runs at ~5.8 TB/s = 92% of the 6.29 TB/s measured copy ceiling.

#define BATCH 64
#define T_LEN 8192
#define FEAT 512
#define HID 256
#define SPLIT 32                       // blocks per batch in pool pass
#define ROWS_PER_BLOCK (T_LEN / SPLIT) // 256
#define ROWS_PER_WAVE 64
#define ITERS (ROWS_PER_WAVE / 8)      // 8

typedef float f4 __attribute__((ext_vector_type(4)));

__device__ __forceinline__ f4 ntl(const f4* p) { return __builtin_nontemporal_load(p); }
__device__ __forceinline__ float hsum(f4 v) { return (v.x + v.y) + (v.z + v.w); }

// DPP add: x + permuted(x). CTRL: 0xB1 quad_perm xor1, 0x4E quad_perm xor2,
// 0x128 row_ror:8, 0x124 row_ror:4 (row = 16 lanes).
template <int CTRL>
__device__ __forceinline__ float dpp_add(float x) {
    int y = __builtin_amdgcn_update_dpp(0, __float_as_int(x), CTRL, 0xF, 0xF, true);
    return x + __int_as_float(y);
}
// 16-lane allreduce: quads sum via xor1/xor2, then ror8 pairs q0+q2|q1+q3,
// ror4 combines the two pair-sums -> every lane holds the row total.
__device__ __forceinline__ float row16_allreduce(float x) {
    x = dpp_add<0xB1>(x);
    x = dpp_add<0x4E>(x);
    x = dpp_add<0x128>(x);
    x = dpp_add<0x124>(x);
    return x;
}

// ---------------- Kernel 1: AP = tanh(A @ W^T + bias) ----------------
// grid (4, BATCH), 256 thr. Block (p,b) computes AP[b][p*64 .. p*64+63].
// 16 lanes per output row; W rows read directly (L2-hot), no LDS staging.
__global__ __launch_bounds__(256) void ap_kernel(const float* __restrict__ A,
                                                 const float* __restrict__ W,
                                                 const float* __restrict__ bias,
                                                 float* __restrict__ AP) {
    const int p = blockIdx.x;
    const int b = blockIdx.y;
    const int tid = threadIdx.x;
    const int pos = tid & 15;

    __shared__ float sA[FEAT];
    sA[tid] = A[b * FEAT + tid];
    sA[tid + 256] = A[b * FEAT + tid + 256];
    __syncthreads();

    // A fragment in regs: a[j] covers k = 4*pos + 64*j .. +3
    const f4* sA4 = (const f4*)sA;
    f4 a0 = sA4[pos],      a1 = sA4[pos + 16], a2 = sA4[pos + 32], a3 = sA4[pos + 48];
    f4 a4 = sA4[pos + 64], a5 = sA4[pos + 80], a6 = sA4[pos + 96], a7 = sA4[pos + 112];

    #pragma unroll
    for (int pass = 0; pass < 4; ++pass) {
        const int h = p * 64 + pass * 16 + (tid >> 4);
        const f4* Wr = (const f4*)(W + (size_t)h * FEAT);
        f4 m = Wr[pos] * a0 + Wr[pos + 16] * a1 + Wr[pos + 32] * a2 + Wr[pos + 48] * a3
             + Wr[pos + 64] * a4 + Wr[pos + 80] * a5 + Wr[pos + 96] * a6 + Wr[pos + 112] * a7;
        float s = row16_allreduce(hsum(m));
        if (pos == 0) AP[b * HID + h] = tanhf(s + bias[h]);
    }
}

// ---------------- Kernel 2: fused score+exp+weighted-accumulate ----------------
// grid = (SPLIT, BATCH), 256 threads = 4 waves; wave owns 64 consecutive rows.
// Lane (sub = lane>>4, pos = lane&15): group-A row = base + sub, group-B row =
// base + 4 + sub. Per-instruction footprint: 4 rows x 256B contiguous segments.
__global__ __launch_bounds__(256) void pool_kernel(const float* __restrict__ B,
                                                   const float* __restrict__ AP,
                                                   float* __restrict__ numP,
                                                   float* __restrict__ denP) {
    const int split = blockIdx.x;
    const int b = blockIdx.y;
    const int tid = threadIdx.x;
    const int wv = tid >> 6;
    const int lane = tid & 63;
    const int sub = lane >> 4;
    const int pos = lane & 15;

    const f4* __restrict__ AP4 = (const f4*)(AP + b * HID);
    const f4 ap0 = AP4[pos];
    const f4 ap1 = AP4[pos + 16];
    const f4 ap2 = AP4[pos + 32];
    const f4 ap3 = AP4[pos + 48];

    const f4* __restrict__ B4 = (const f4*)(B) + (size_t)b * T_LEN * (HID / 4);
    const int row0 = split * ROWS_PER_BLOCK + wv * ROWS_PER_WAVE;

    f4 acc0 = {0.f,0.f,0.f,0.f}, acc1 = {0.f,0.f,0.f,0.f};
    f4 acc2 = {0.f,0.f,0.f,0.f}, acc3 = {0.f,0.f,0.f,0.f};
    float den = 0.0f;

    // prologue: load iteration 0 (rows base+sub and base+4+sub)
    const f4* pa = B4 + (size_t)(row0 + sub) * (HID / 4);
    const f4* pb = pa + 4 * (HID / 4);
    f4 vA0 = ntl(pa + pos), vA1 = ntl(pa + pos + 16), vA2 = ntl(pa + pos + 32), vA3 = ntl(pa + pos + 48);
    f4 vB0 = ntl(pb + pos), vB1 = ntl(pb + pos + 16), vB2 = ntl(pb + pos + 32), vB3 = ntl(pb + pos + 48);

    #pragma unroll
    for (int it = 0; it < ITERS; ++it) {
        // 1-iteration prefetch; PEELED on the last iteration (it+1 test is
        // compile-time under full unroll) — no redundant nt re-reads from HBM.
        f4 nA0, nA1, nA2, nA3, nB0, nB1, nB2, nB3;
        if (it + 1 < ITERS) {
            const f4* na = B4 + (size_t)(row0 + (it + 1) * 8 + sub) * (HID / 4);
            const f4* nb = na + 4 * (HID / 4);
            nA0 = ntl(na + pos); nA1 = ntl(na + pos + 16); nA2 = ntl(na + pos + 32); nA3 = ntl(na + pos + 48);
            nB0 = ntl(nb + pos); nB1 = ntl(nb + pos + 16); nB2 = ntl(nb + pos + 32); nB3 = ntl(nb + pos + 48);
        }

        f4 mA = vA0 * ap0 + vA1 * ap1 + vA2 * ap2 + vA3 * ap3;
        f4 mB = vB0 * ap0 + vB1 * ap1 + vB2 * ap2 + vB3 * ap3;
        float pAs = hsum(mA);
        float pBs = hsum(mB);

        // two independent 16-lane DPP allreduces — VALU-latency, interleaved
        pAs = dpp_add<0xB1>(pAs);  pBs = dpp_add<0xB1>(pBs);
        pAs = dpp_add<0x4E>(pAs);  pBs = dpp_add<0x4E>(pBs);
        pAs = dpp_add<0x128>(pAs); pBs = dpp_add<0x128>(pBs);
        pAs = dpp_add<0x124>(pAs); pBs = dpp_add<0x124>(pBs);

        const float wA = __expf(-pAs);
        const float wB = __expf(-pBs);
        acc0 += wA * vA0 + wB * vB0;
        acc1 += wA * vA1 + wB * vB1;
        acc2 += wA * vA2 + wB * vB2;
        acc3 += wA * vA3 + wB * vB3;
        den += wA + wB;

        if (it + 1 < ITERS) {
            vA0 = nA0; vA1 = nA1; vA2 = nA2; vA3 = nA3;
            vB0 = nB0; vB1 = nB1; vB2 = nB2; vB3 = nB3;
        }
    }

    // reduce accumulators across the 4 sub-groups (lane bits 4,5)
    #define XRED(x) x += __shfl_xor(x, 16, 64); x += __shfl_xor(x, 32, 64)
    XRED(acc0.x); XRED(acc0.y); XRED(acc0.z); XRED(acc0.w);
    XRED(acc1.x); XRED(acc1.y); XRED(acc1.z); XRED(acc1.w);
    XRED(acc2.x); XRED(acc2.y); XRED(acc2.z); XRED(acc2.w);
    XRED(acc3.x); XRED(acc3.y); XRED(acc3.z); XRED(acc3.w);
    XRED(den);
    #undef XRED

    // combine 4 waves via LDS, write per-block partials
    __shared__ float s_num[4][HID];
    __shared__ float s_den[4];
    if (sub == 0) {
        f4* dst = (f4*)s_num[wv];
        dst[pos]      = acc0;
        dst[pos + 16] = acc1;
        dst[pos + 32] = acc2;
        dst[pos + 48] = acc3;
    }
    if (lane == 0) s_den[wv] = den;
    __syncthreads();

    const int blk = b * SPLIT + split;
    float n = s_num[0][tid] + s_num[1][tid] + s_num[2][tid] + s_num[3][tid];
    numP[(size_t)blk * HID + tid] = n;
    if (tid == 0) denP[blk] = s_den[0] + s_den[1] + s_den[2] + s_den[3];
}

// ---------------- Kernel 3: reduce partials, normalize ----------------
__global__ __launch_bounds__(256) void reduce_kernel(const float* __restrict__ numP,
                                                     const float* __restrict__ denP,
                                                     float* __restrict__ out) {
    const int b = blockIdx.x;
    const int h = threadIdx.x;
    float num = 0.0f, den = 0.0f;
    #pragma unroll
    for (int s = 0; s < SPLIT; ++s) {
        num += numP[(size_t)(b * SPLIT + s) * HID + h];
        den += denP[b * SPLIT + s];
    }
    out[b * HID + h] = num / den;
}

extern "C" void kernel_launch(void* const* d_in, const int* in_sizes, int n_in,
                              void* d_out, int out_size, void* d_ws, size_t ws_size,
                              hipStream_t stream) {
    const float* A = (const float*)d_in[0];    // [64,512]
    const float* B = (const float*)d_in[1];    // [64,8192,256]
    const float* W = (const float*)d_in[2];    // [256,512]
    const float* bias = (const float*)d_in[3]; // [256]
    float* out = (float*)d_out;                // [64,1,256]

    float* AP = (float*)d_ws;
    float* numP = AP + BATCH * HID;
    float* denP = numP + BATCH * SPLIT * HID;

    ap_kernel<<<dim3(4, BATCH), 256, 0, stream>>>(A, W, bias, AP);
    pool_kernel<<<dim3(SPLIT, BATCH), 256, 0, stream>>>(B, AP, numP, denP);
    reduce_kernel<<<BATCH, 256, 0, stream>>>(numP, denP, out);
}